// Round 5
// baseline (180.167 us; speedup 1.0000x reference)
//
#include <hip/hip_runtime.h>

// Problem constants (from reference): B=16, K=64, H=160, W=160
#define KK 64
#define HH 160
#define WW 160
#define HWPIX (HH * WW)   // 25600
#define EPSF 1e-5f

// Grid splits the k-store dimension into KGROUPS groups to raise wave-level
// parallelism (1600 blocks / 6400 waves vs 400/1600): each block recomputes
// the full 64-k denominator (cheap, trans-unit work that overlaps stores)
// but stores only KK/KGROUPS k-slices.
#define KGROUPS 4
#define KPER (KK / KGROUPS)   // 16

// Each thread owns 4 consecutive pixels (same row: W=160 % 4 == 0).
// Phase 1: accumulate the 4 softmax-style denominators over all 64 keypoints.
// Phase 2: recompute exp for this block's 16 k's, scale, plain float4 store
// (non-NT: round-1 evidence suggests the nt path writes slower here).
// den cancels algebraically: out = e_k / (sum_k e + EPS/den).
__global__ __launch_bounds__(256) void recon_confmap_fused(
    const float* __restrict__ kp,     // [B, K, 2] (x, y)
    const float* __restrict__ sx_p,
    const float* __restrict__ sy_p,
    const float* __restrict__ rho_p,
    float* __restrict__ out)          // [B, K, H, W]
{
    __shared__ float2 skp[KK];

    const int b     = blockIdx.z;
    const int kbase = blockIdx.y * KPER;
    const int tid   = threadIdx.x;
    if (tid < KK) skp[tid] = ((const float2*)(kp + (size_t)b * KK * 2))[tid];

    const float sx  = sx_p[0];
    const float sy  = sy_p[0];
    const float rho = rho_p[0];
    __syncthreads();

    const float L2E  = 1.44269504088896340736f;
    const float omr2 = 1.0f - rho * rho;
    const float num1 = -0.5f / omr2;
    const float ca   = num1 / (sy * sy) * L2E;                 // * dy^2
    const float cb   = num1 / (sx * sx) * L2E;                 // * dx^2
    const float cc   = num1 * (-2.0f * rho / (sx * sy)) * L2E; // * dy*dx
    const float epsod = EPSF * (2.0f * 3.14159265358979323846f * sx * sy * sqrtf(omr2));

    const int p0 = blockIdx.x * 1024 + tid * 4;  // grid.x = HWPIX/1024 = 25
    const int i  = p0 / WW;
    const int j  = p0 - i * WW;
    const float fi = (float)i;
    const float fj = (float)j;

    // ---- Phase 1: denominators for the 4 pixels (all 64 keypoints) ----
    float s0 = 0.0f, s1 = 0.0f, s2 = 0.0f, s3 = 0.0f;
#pragma unroll
    for (int k = 0; k < KK; ++k) {
        const float dy  = fi - skp[k].y;
        const float ady = ca * dy * dy;
        const float cdy = cc * dy;
        const float dx0 = fj - skp[k].x;
        const float dx1 = dx0 + 1.0f;
        const float dx2 = dx0 + 2.0f;
        const float dx3 = dx0 + 3.0f;
        s0 += __builtin_amdgcn_exp2f(fmaf(cdy, dx0, fmaf(cb * dx0, dx0, ady)));
        s1 += __builtin_amdgcn_exp2f(fmaf(cdy, dx1, fmaf(cb * dx1, dx1, ady)));
        s2 += __builtin_amdgcn_exp2f(fmaf(cdy, dx2, fmaf(cb * dx2, dx2, ady)));
        s3 += __builtin_amdgcn_exp2f(fmaf(cdy, dx3, fmaf(cb * dx3, dx3, ady)));
    }

    const float i0 = 1.0f / (s0 + epsod);
    const float i1 = 1.0f / (s1 + epsod);
    const float i2 = 1.0f / (s2 + epsod);
    const float i3 = 1.0f / (s3 + epsod);

    // ---- Phase 2: this block's 16 k-slices: recompute, scale, store ----
    float* op = out + (size_t)b * KK * HWPIX + (size_t)kbase * HWPIX + p0;
#pragma unroll
    for (int kk = 0; kk < KPER; ++kk) {
        const int k = kbase + kk;
        const float dy  = fi - skp[k].y;
        const float ady = ca * dy * dy;
        const float cdy = cc * dy;
        const float dx0 = fj - skp[k].x;
        const float dx1 = dx0 + 1.0f;
        const float dx2 = dx0 + 2.0f;
        const float dx3 = dx0 + 3.0f;
        float4 o;
        o.x = __builtin_amdgcn_exp2f(fmaf(cdy, dx0, fmaf(cb * dx0, dx0, ady))) * i0;
        o.y = __builtin_amdgcn_exp2f(fmaf(cdy, dx1, fmaf(cb * dx1, dx1, ady))) * i1;
        o.z = __builtin_amdgcn_exp2f(fmaf(cdy, dx2, fmaf(cb * dx2, dx2, ady))) * i2;
        o.w = __builtin_amdgcn_exp2f(fmaf(cdy, dx3, fmaf(cb * dx3, dx3, ady))) * i3;
        *(float4*)(op + (size_t)kk * HWPIX) = o;
    }
}

extern "C" void kernel_launch(void* const* d_in, const int* in_sizes, int n_in,
                              void* d_out, int out_size, void* d_ws, size_t ws_size,
                              hipStream_t stream) {
    const float* kp    = (const float*)d_in[0];  // keypoints [B,K,2]
    const float* sx_p  = (const float*)d_in[1];
    const float* sy_p  = (const float*)d_in[2];
    const float* rho_p = (const float*)d_in[3];
    // d_in[4] = DetectionMap: values unused by the reference (shape only)
    float* out = (float*)d_out;

    const int B = in_sizes[0] / (KK * 2);   // 16
    dim3 grid(HWPIX / 1024, KGROUPS, B);    // (25, 4, 16) = 1600 blocks
    recon_confmap_fused<<<grid, 256, 0, stream>>>(kp, sx_p, sy_p, rho_p, out);
}

// Round 6
// 169.608 us; speedup vs baseline: 1.0623x; 1.0623x over previous
//
#include <hip/hip_runtime.h>

// Problem constants (from reference): B=16, K=64, H=160, W=160
#define KK 64
#define HH 160
#define WW 160
#define HWPIX (HH * WW)   // 25600
#define EPSF 1e-5f

// Work-minimal structure (round-1 class, best measured): one thread per
// output pixel (b,i,j); each exp2 computed EXACTLY ONCE (26.2M total),
// kept in a 64-entry register array; wave stores are 256B-contiguous
// dword streams per k-slice (fully coalesced).
//   out = e_k / (sum_k e + EPS/den)   [den cancels algebraically]
// Micro-cleanups vs round 1: v_rcp_f32 instead of IEEE divide sequence
// (tolerance 2e-2 >> rcp's ~1e-7), hoisted 64-bit output base.
__global__ __launch_bounds__(256) void recon_confmap_kernel(
    const float* __restrict__ kp,     // [B, K, 2]  (x, y)
    const float* __restrict__ sx_p,
    const float* __restrict__ sy_p,
    const float* __restrict__ rho_p,
    float* __restrict__ out)          // [B, K, H, W]
{
    __shared__ float2 skp[KK];

    const int b   = blockIdx.y;
    const int tid = threadIdx.x;

    if (tid < KK) {
        skp[tid] = ((const float2*)(kp + (size_t)b * KK * 2))[tid];
    }

    const float sx  = sx_p[0];
    const float sy  = sy_p[0];
    const float rho = rho_p[0];
    __syncthreads();

    const float L2E  = 1.44269504088896340736f;
    const float omr2 = 1.0f - rho * rho;
    const float num1 = -0.5f / omr2;
    const float ca   = num1 / (sy * sy) * L2E;                 // * dy^2
    const float cb   = num1 / (sx * sx) * L2E;                 // * dx^2
    const float cc   = num1 * (-2.0f * rho / (sx * sy)) * L2E; // * dy*dx
    const float epsod = EPSF * (2.0f * 3.14159265358979323846f * sx * sy * sqrtf(omr2));

    const int p  = blockIdx.x * 256 + tid;   // grid.x = HWPIX/256 = 100
    const int i  = p / WW;
    const int j  = p - i * WW;
    const float fi = (float)i;
    const float fj = (float)j;

    float s[KK];
    float sum = 0.0f;
#pragma unroll
    for (int k = 0; k < KK; ++k) {
        const float dy  = fi - skp[k].y;
        const float dx  = fj - skp[k].x;
        const float arg = fmaf(ca * dy, dy, fmaf(cb * dx, dx, cc * dy * dx));
        const float e   = __builtin_amdgcn_exp2f(arg);
        s[k] = e;
        sum += e;
    }

    const float inv = __builtin_amdgcn_rcpf(sum + epsod);

    float* op = out + (size_t)b * KK * HWPIX + p;
#pragma unroll
    for (int k = 0; k < KK; ++k) {
        op[(size_t)k * HWPIX] = s[k] * inv;
    }
}

extern "C" void kernel_launch(void* const* d_in, const int* in_sizes, int n_in,
                              void* d_out, int out_size, void* d_ws, size_t ws_size,
                              hipStream_t stream) {
    const float* kp    = (const float*)d_in[0];  // keypoints [B,K,2]
    const float* sx_p  = (const float*)d_in[1];
    const float* sy_p  = (const float*)d_in[2];
    const float* rho_p = (const float*)d_in[3];
    // d_in[4] = DetectionMap: values unused by the reference (shape only)
    float* out = (float*)d_out;

    const int B = in_sizes[0] / (KK * 2);   // 16
    dim3 grid(HWPIX / 256, B);              // (100, 16) = 1600 blocks
    recon_confmap_kernel<<<grid, 256, 0, stream>>>(kp, sx_p, sy_p, rho_p, out);
}